// Round 1
// baseline (577.074 us; speedup 1.0000x reference)
//
#include <hip/hip_runtime.h>
#include <math.h>

// Fused per-batch multi-head attention block + FFN for
// B=4096, T=64, C=64, H=8, D=8 (fp32 in/out, fp32 VALU compute).
//
// One workgroup (512 threads = 8 waves) per batch element.
// Thread mapping, attention phase: tid -> (h = tid>>6, t = tid&63).
//   - q[h,t,:] lives in registers of its owning thread.
//   - k,v for all (s) rows live in LDS; inner-loop reads are
//     wave-uniform addresses (same h, same s across the wave) -> broadcast,
//     conflict-free.
//   - 64 score registers per thread, softmax fully in-thread (no shuffles).
// LDS: xs [64][65] (x tile, reused for concat-head attention output 'att'),
//      ks/vs [64][68] (stride 68 keeps float4 alignment).
// Total LDS = 51456 B -> 3 blocks/CU by LDS; VGPR ~120 -> ~2 blocks/CU.

constexpr int Tt = 64;
constexpr int Cc = 64;
constexpr int Dh = 8;

__global__ __launch_bounds__(512, 2) void mha_fused_kernel(
    const float* __restrict__ x,
    const float* __restrict__ Wq,
    const float* __restrict__ Wk,
    const float* __restrict__ Wv,
    const float* __restrict__ W1,
    const float* __restrict__ b1,
    float* __restrict__ y)
{
    __shared__ float xs[Tt * 65];   // x tile; later reused as att (B,T,H*D)
    __shared__ float ks[Tt * 68];
    __shared__ float vs[Tt * 68];

    const int b   = blockIdx.x;
    const int tid = threadIdx.x;

    // ---------------- stage x[b] into LDS ----------------
    const float* xb = x + (size_t)b * (Tt * Cc);
    #pragma unroll
    for (int i = 0; i < 2; ++i) {
        int f = i * 512 + tid;              // float4 index, 0..1023 (coalesced)
        float4 v4 = ((const float4*)xb)[f];
        int r  = f >> 4;                    // 16 float4 per row
        int c0 = (f & 15) * 4;
        float* p = &xs[r * 65 + c0];        // scalar stores (65-stride unaligned for b128)
        p[0] = v4.x; p[1] = v4.y; p[2] = v4.z; p[3] = v4.w;
    }
    __syncthreads();

    const int t  = tid & 63;   // time row
    const int h  = tid >> 6;   // head
    const int h8 = h * Dh;

    // ---------------- projections: q->regs, k,v->LDS ----------------
    float q[8];
    {
        float aq[8], ak[8], av[8];
        #pragma unroll
        for (int d = 0; d < 8; ++d) { aq[d] = 0.f; ak[d] = 0.f; av[d] = 0.f; }
        const float* wq = Wq + h * (Cc * Dh);
        const float* wk = Wk + h * (Cc * Dh);
        const float* wv = Wv + h * (Cc * Dh);
        for (int c = 0; c < Cc; ++c) {
            float s = xs[t * 65 + c];       // banks (t+c)%32 -> 2-way, free
            float wq8[8], wk8[8], wv8[8];   // wave-uniform addrs -> cached/broadcast
            *(float4*)&wq8[0] = *(const float4*)(wq + c * 8);
            *(float4*)&wq8[4] = *(const float4*)(wq + c * 8 + 4);
            *(float4*)&wk8[0] = *(const float4*)(wk + c * 8);
            *(float4*)&wk8[4] = *(const float4*)(wk + c * 8 + 4);
            *(float4*)&wv8[0] = *(const float4*)(wv + c * 8);
            *(float4*)&wv8[4] = *(const float4*)(wv + c * 8 + 4);
            #pragma unroll
            for (int d = 0; d < 8; ++d) {
                aq[d] += s * wq8[d];
                ak[d] += s * wk8[d];
                av[d] += s * wv8[d];
            }
        }
        #pragma unroll
        for (int d = 0; d < 8; ++d) q[d] = aq[d];
        // one-time writes; minor conflicts acceptable
        *(float4*)&ks[t * 68 + h8]     = *(float4*)&ak[0];
        *(float4*)&ks[t * 68 + h8 + 4] = *(float4*)&ak[4];
        *(float4*)&vs[t * 68 + h8]     = *(float4*)&av[0];
        *(float4*)&vs[t * 68 + h8 + 4] = *(float4*)&av[4];
    }
    __syncthreads();

    // ---------------- attention: scores + softmax + PV, all in-thread ----------------
    float sc[64];
    #pragma unroll
    for (int s = 0; s < 64; ++s) {
        float k8[8];                        // wave-uniform addr -> LDS broadcast
        *(float4*)&k8[0] = *(const float4*)&ks[s * 68 + h8];
        *(float4*)&k8[4] = *(const float4*)&ks[s * 68 + h8 + 4];
        float d0 = 0.f;
        #pragma unroll
        for (int d = 0; d < 8; ++d) d0 += q[d] * k8[d];
        sc[s] = (s <= t) ? d0 * 0.125f : -INFINITY;   // scale = C^-0.5 = 1/8
    }
    // max: 8 partial chains to cut serial latency
    float m = -INFINITY;
    {
        float pm[8];
        #pragma unroll
        for (int j = 0; j < 8; ++j) pm[j] = sc[j];
        #pragma unroll
        for (int s = 8; s < 64; ++s) pm[s & 7] = fmaxf(pm[s & 7], sc[s]);
        #pragma unroll
        for (int j = 0; j < 8; ++j) m = fmaxf(m, pm[j]);
    }
    float l;
    {
        float pl[8];
        #pragma unroll
        for (int j = 0; j < 8; ++j) pl[j] = 0.f;
        #pragma unroll
        for (int s = 0; s < 64; ++s) {
            float p = __expf(sc[s] - m);    // exp(-inf)=0 handles the causal mask
            sc[s] = p;
            pl[s & 7] += p;
        }
        l = ((pl[0] + pl[1]) + (pl[2] + pl[3])) + ((pl[4] + pl[5]) + (pl[6] + pl[7]));
    }
    float o[8];
    #pragma unroll
    for (int d = 0; d < 8; ++d) o[d] = 0.f;
    #pragma unroll
    for (int s = 0; s < 64; ++s) {
        float v8[8];                        // wave-uniform addr -> LDS broadcast
        *(float4*)&v8[0] = *(const float4*)&vs[s * 68 + h8];
        *(float4*)&v8[4] = *(const float4*)&vs[s * 68 + h8 + 4];
        float p = sc[s];
        #pragma unroll
        for (int d = 0; d < 8; ++d) o[d] += p * v8[d];
    }
    const float inv = 1.0f / l;
    // att[t][h*8+d] = out; xs reuse is safe: all xs reads completed before the
    // post-projection barrier above.
    #pragma unroll
    for (int d = 0; d < 8; ++d) xs[t * 65 + h8 + d] = o[d] * inv;
    __syncthreads();

    // ---------------- FFN: y = relu(att @ W1 + b1) ----------------
    {
        const int r  = tid >> 3;            // row
        const int j0 = (tid & 7) * 8;       // output cols
        float acc[8];
        *(float4*)&acc[0] = *(const float4*)&b1[j0];
        *(float4*)&acc[4] = *(const float4*)&b1[j0 + 4];
        for (int c = 0; c < Cc; ++c) {
            float s = xs[r * 65 + c];       // 8 addrs x 8-lane broadcast, conflict-free
            float w8[8];
            *(float4*)&w8[0] = *(const float4*)&W1[c * 64 + j0];
            *(float4*)&w8[4] = *(const float4*)&W1[c * 64 + j0 + 4];
            #pragma unroll
            for (int d = 0; d < 8; ++d) acc[d] += s * w8[d];
        }
        float* yb = y + (size_t)b * (Tt * Cc) + r * 64 + j0;
        float4 o0, o1;
        o0.x = fmaxf(acc[0], 0.f); o0.y = fmaxf(acc[1], 0.f);
        o0.z = fmaxf(acc[2], 0.f); o0.w = fmaxf(acc[3], 0.f);
        o1.x = fmaxf(acc[4], 0.f); o1.y = fmaxf(acc[5], 0.f);
        o1.z = fmaxf(acc[6], 0.f); o1.w = fmaxf(acc[7], 0.f);
        *(float4*)&yb[0] = o0;
        *(float4*)&yb[4] = o1;
    }
}

extern "C" void kernel_launch(void* const* d_in, const int* in_sizes, int n_in,
                              void* d_out, int out_size, void* d_ws, size_t ws_size,
                              hipStream_t stream) {
    const float* x  = (const float*)d_in[0];
    const float* Wq = (const float*)d_in[1];
    const float* Wk = (const float*)d_in[2];
    const float* Wv = (const float*)d_in[3];
    const float* W1 = (const float*)d_in[4];
    const float* b1 = (const float*)d_in[5];
    float* y = (float*)d_out;

    const int B = in_sizes[0] / (Tt * Cc);  // 4096
    mha_fused_kernel<<<B, 512, 0, stream>>>(x, Wq, Wk, Wv, W1, b1, y);
}

// Round 2
// 239.488 us; speedup vs baseline: 2.4096x; 2.4096x over previous
//
#include <hip/hip_runtime.h>
#include <hip/hip_bf16.h>
#include <math.h>

// B=4096, T=64, C=64, H=8, D=8. fp32 in/out.
// prep_weights: transpose Wq/Wk/Wv/W1 into d_ws as bf16, B-fragment layout:
//   ws[0 .. 192*64)      : WqkvT[n][c], n = (q:0-63 | k:64-127 | v:128-191), col n = h*8+d
//   ws[12288 .. 16384)   : W1T[j][c]
// Main kernel: 1 block (512 thr, 8 waves) per batch:
//   stage x->bf16 LDS -> MFMA QKV GEMM -> LDS fp32 -> VALU online-softmax
//   attention -> att bf16 in LDS -> MFMA FFN -> relu -> global.

typedef __attribute__((ext_vector_type(8))) short short8;   // 8 bf16 (4 VGPR)
typedef __attribute__((ext_vector_type(4))) float f32x4;

constexpr int Tt = 64, Cc = 64;

__global__ void prep_weights(const float* __restrict__ Wq,
                             const float* __restrict__ Wk,
                             const float* __restrict__ Wv,
                             const float* __restrict__ W1,
                             __hip_bfloat16* __restrict__ ws)
{
    int i = blockIdx.x * 256 + threadIdx.x;      // grid covers 16384
    if (i < 12288) {                             // WqkvT region
        int n = i >> 6, c = i & 63;
        int sec = n >> 6;                        // 0=q 1=k 2=v
        const float* src = (sec == 0) ? Wq : (sec == 1) ? Wk : Wv;
        int h = (n & 63) >> 3, d = n & 7;
        ws[i] = __float2bfloat16(src[h * 512 + c * 8 + d]);   // WT[n][c]=W[h][c][d]
    } else {                                     // W1T region
        int j = (i - 12288) >> 6, c = i & 63;
        ws[i] = __float2bfloat16(W1[c * 64 + j]);             // W1T[j][c]=W1[c][j]
    }
}

__global__ __launch_bounds__(512, 4) void mha_mfma_kernel(
    const float* __restrict__ x,
    const __hip_bfloat16* __restrict__ wT,
    const float* __restrict__ b1v,
    float* __restrict__ y)
{
    __shared__ __hip_bfloat16 xs[Tt * 72];   // x bf16 A-layout (pad->stride 72); reused for att
    __shared__ float qkv[Tt * 196];          // fp32, cols 0-63 Q | 64-127 K | 128-191 V

    const int b    = blockIdx.x;
    const int tid  = threadIdx.x;
    const int lane = tid & 63;
    const int w    = tid >> 6;               // wave id 0..7
    const int l15  = lane & 15;
    const int quad = lane >> 4;

    // ---------------- stage x -> bf16 LDS ----------------
    {
        int r = tid >> 3, c0 = (tid & 7) * 8;
        const float* xp = x + (size_t)b * 4096 + r * 64 + c0;
        float4 a = *(const float4*)xp;
        float4 bq = *(const float4*)(xp + 4);
        union { __hip_bfloat16 h[8]; float4 f; } u;
        u.h[0] = __float2bfloat16(a.x);  u.h[1] = __float2bfloat16(a.y);
        u.h[2] = __float2bfloat16(a.z);  u.h[3] = __float2bfloat16(a.w);
        u.h[4] = __float2bfloat16(bq.x); u.h[5] = __float2bfloat16(bq.y);
        u.h[6] = __float2bfloat16(bq.z); u.h[7] = __float2bfloat16(bq.w);
        *(float4*)&xs[r * 72 + c0] = u.f;    // 16B aligned: 144r + 2c0
    }
    __syncthreads();

    // ---------------- GEMM1: QKV = x @ Wqkv (MFMA) ----------------
    {
        const int wm = (w & 3) * 16;          // M tile
        const int wn = (w >> 2) * 96;         // N half: cols 0-95 / 96-191
        // A frags (shared across col tiles), K-steps 0,1
        short8 a0 = *(const short8*)&xs[(wm + l15) * 72 + quad * 8];
        short8 a1 = *(const short8*)&xs[(wm + l15) * 72 + 32 + quad * 8];
        #pragma unroll
        for (int ct = 0; ct < 6; ++ct) {
            int col = wn + ct * 16 + l15;
            const __hip_bfloat16* bp = wT + col * 64 + quad * 8;
            short8 b0 = *(const short8*)bp;          // global, L1-hot
            short8 b1f = *(const short8*)(bp + 32);
            f32x4 acc = {0.f, 0.f, 0.f, 0.f};
            acc = __builtin_amdgcn_mfma_f32_16x16x32_bf16(a0, b0, acc, 0, 0, 0);
            acc = __builtin_amdgcn_mfma_f32_16x16x32_bf16(a1, b1f, acc, 0, 0, 0);
            int row0 = wm + quad * 4;                // C layout: col=lane&15, row=quad*4+r
            #pragma unroll
            for (int r = 0; r < 4; ++r)
                qkv[(row0 + r) * 196 + col] = acc[r];   // 2-way bank alias: free
        }
    }
    __syncthreads();

    // ---------------- attention (VALU, online softmax) ----------------
    const int t = lane, h8 = w * 8;
    {
        float q[8];
        *(float4*)&q[0] = *(const float4*)&qkv[t * 196 + h8];
        *(float4*)&q[4] = *(const float4*)&qkv[t * 196 + h8 + 4];
        float m = -INFINITY, l = 0.f;
        float o[8];
        #pragma unroll
        for (int d = 0; d < 8; ++d) o[d] = 0.f;
        for (int s = 0; s < 64; ++s) {
            float k8[8], v8[8];                  // wave-uniform -> broadcast reads
            *(float4*)&k8[0] = *(const float4*)&qkv[s * 196 + 64 + h8];
            *(float4*)&k8[4] = *(const float4*)&qkv[s * 196 + 64 + h8 + 4];
            *(float4*)&v8[0] = *(const float4*)&qkv[s * 196 + 128 + h8];
            *(float4*)&v8[4] = *(const float4*)&qkv[s * 196 + 128 + h8 + 4];
            float d0 = 0.f;
            #pragma unroll
            for (int d = 0; d < 8; ++d) d0 += q[d] * k8[d];
            float sc = (s <= t) ? d0 * 0.125f : -INFINITY;   // causal, scale C^-0.5
            float mn = fmaxf(m, sc);
            float alpha = __expf(m - mn);        // s=0: exp(-inf)=0, no NaN
            float p = __expf(sc - mn);
            l = l * alpha + p;
            #pragma unroll
            for (int d = 0; d < 8; ++d) o[d] = o[d] * alpha + p * v8[d];
            m = mn;
        }
        float inv = 1.f / l;
        union { __hip_bfloat16 hh[8]; float4 f; } u;
        #pragma unroll
        for (int d = 0; d < 8; ++d) u.hh[d] = __float2bfloat16(o[d] * inv);
        *(float4*)&xs[t * 72 + h8] = u.f;        // att[t][h*8+d], xs reuse (post-barrier)
    }
    __syncthreads();

    // ---------------- FFN: y = relu(att @ W1 + b1) (MFMA) ----------------
    {
        const int wm = (w & 3) * 16;
        const int wn = (w >> 2) * 32;
        short8 a0 = *(const short8*)&xs[(wm + l15) * 72 + quad * 8];
        short8 a1 = *(const short8*)&xs[(wm + l15) * 72 + 32 + quad * 8];
        const __hip_bfloat16* w1t = wT + 192 * 64;
        #pragma unroll
        for (int nt = 0; nt < 2; ++nt) {
            int col = wn + nt * 16 + l15;
            const __hip_bfloat16* bp = w1t + col * 64 + quad * 8;
            short8 b0 = *(const short8*)bp;
            short8 b1f = *(const short8*)(bp + 32);
            f32x4 acc = {0.f, 0.f, 0.f, 0.f};
            acc = __builtin_amdgcn_mfma_f32_16x16x32_bf16(a0, b0, acc, 0, 0, 0);
            acc = __builtin_amdgcn_mfma_f32_16x16x32_bf16(a1, b1f, acc, 0, 0, 0);
            float bias = b1v[col];
            float* yp = y + (size_t)b * 4096 + col;
            int row0 = wm + quad * 4;
            #pragma unroll
            for (int r = 0; r < 4; ++r)
                yp[(row0 + r) * 64] = fmaxf(acc[r] + bias, 0.f);
        }
    }
}

extern "C" void kernel_launch(void* const* d_in, const int* in_sizes, int n_in,
                              void* d_out, int out_size, void* d_ws, size_t ws_size,
                              hipStream_t stream) {
    const float* x  = (const float*)d_in[0];
    const float* Wq = (const float*)d_in[1];
    const float* Wk = (const float*)d_in[2];
    const float* Wv = (const float*)d_in[3];
    const float* W1 = (const float*)d_in[4];
    const float* b1 = (const float*)d_in[5];
    float* y = (float*)d_out;
    __hip_bfloat16* ws = (__hip_bfloat16*)d_ws;

    const int B = in_sizes[0] / (Tt * Cc);       // 4096
    prep_weights<<<64, 256, 0, stream>>>(Wq, Wk, Wv, W1, ws);
    mha_mfma_kernel<<<B, 512, 0, stream>>>(x, ws, b1, y);
}

// Round 3
// 164.032 us; speedup vs baseline: 3.5181x; 1.4600x over previous
//
#include <hip/hip_runtime.h>
#include <hip/hip_bf16.h>
#include <math.h>

// B=4096, T=64, C=64, H=8, D=8. fp32 in/out.
// prep_weights -> d_ws bf16: WqkvT[n][c] (n: q 0-63 | k 64-127 | v 128-191),
// then W1T[j][c]. Main kernel: 256 thr (4 waves) per batch element.
//   phase0: x -> bf16 LDS xs[64][72]
//   phase1: QKV = x@Wqkv via MFMA; epilogue scatters bf16 to
//           qh[h][t][d], kh[h][s][d], vth[h][d][s] (V transposed, packed b64)
//   phase2: wave w, heads h=2w,2w+1: S^T = K Q^T via 10 zero-K-padded MFMAs
//           (causal upper-tri only), softmax rows = 16 in-lane + shfl_xor(16,32),
//           normalized P -> bf16 -> per-wave LDS [t][s] (C->A layout xform),
//           O = P V via 8 MFMAs, O -> qh[h] (att concat buffer)
//   phase3: y = relu(att@W1+b1) via MFMA.
// LDS: P-region 4*64*72*2 = 36864 (unioned with xs) + qh 8192 + kh 8192
//      + vth 8*8*72*2 = 9216  => 62464 B -> 2 blocks/CU.

typedef __attribute__((ext_vector_type(8))) short short8;   // 8 bf16
typedef __attribute__((ext_vector_type(4))) float f32x4;

__global__ void prep_weights(const float* __restrict__ Wq,
                             const float* __restrict__ Wk,
                             const float* __restrict__ Wv,
                             const float* __restrict__ W1,
                             __hip_bfloat16* __restrict__ ws)
{
    int i = blockIdx.x * 256 + threadIdx.x;      // 16384 total
    if (i < 12288) {
        int n = i >> 6, c = i & 63;
        int sec = n >> 6;
        const float* src = (sec == 0) ? Wq : (sec == 1) ? Wk : Wv;
        int h = (n & 63) >> 3, d = n & 7;
        ws[i] = __float2bfloat16(src[h * 512 + c * 8 + d]);
    } else {
        int j = (i - 12288) >> 6, c = i & 63;
        ws[i] = __float2bfloat16(W1[c * 64 + j]);
    }
}

__global__ __launch_bounds__(256, 2) void mha_mfma2_kernel(
    const float* __restrict__ x,
    const __hip_bfloat16* __restrict__ wT,
    const float* __restrict__ b1v,
    float* __restrict__ y)
{
    __shared__ __align__(16) __hip_bfloat16 region0[4 * 64 * 72]; // xs | P[w]
    __shared__ __align__(16) __hip_bfloat16 qh[8 * 64 * 8];  // Q[h][t][d] -> later O
    __shared__ __align__(16) __hip_bfloat16 kh[8 * 64 * 8];  // K[h][s][d]
    __shared__ __align__(16) __hip_bfloat16 vth[8 * 8 * 72]; // V^T[h][d][s] stride 72

    const int b    = blockIdx.x;
    const int tid  = threadIdx.x;
    const int lane = tid & 63;
    const int w    = tid >> 6;          // wave 0..3
    const int l15  = lane & 15;
    const int quad = lane >> 4;

    __hip_bfloat16* xs = region0;       // [64][72]

    // ---------------- phase 0: stage x -> bf16 ----------------
    {
        int r = tid >> 2, c0 = (tid & 3) * 16;
        const float* xp = x + (size_t)b * 4096 + r * 64 + c0;
        float4 f0 = ((const float4*)xp)[0];
        float4 f1 = ((const float4*)xp)[1];
        float4 f2 = ((const float4*)xp)[2];
        float4 f3 = ((const float4*)xp)[3];
        union { __hip_bfloat16 h[8]; float4 f; } u0, u1;
        u0.h[0] = __float2bfloat16(f0.x); u0.h[1] = __float2bfloat16(f0.y);
        u0.h[2] = __float2bfloat16(f0.z); u0.h[3] = __float2bfloat16(f0.w);
        u0.h[4] = __float2bfloat16(f1.x); u0.h[5] = __float2bfloat16(f1.y);
        u0.h[6] = __float2bfloat16(f1.z); u0.h[7] = __float2bfloat16(f1.w);
        u1.h[0] = __float2bfloat16(f2.x); u1.h[1] = __float2bfloat16(f2.y);
        u1.h[2] = __float2bfloat16(f2.z); u1.h[3] = __float2bfloat16(f2.w);
        u1.h[4] = __float2bfloat16(f3.x); u1.h[5] = __float2bfloat16(f3.y);
        u1.h[6] = __float2bfloat16(f3.z); u1.h[7] = __float2bfloat16(f3.w);
        *(float4*)&xs[r * 72 + c0]     = u0.f;
        *(float4*)&xs[r * 72 + c0 + 8] = u1.f;
    }
    __syncthreads();

    // ---------------- phase 1: QKV GEMM ----------------
    {
        short8 afr[4][2];
        #pragma unroll
        for (int tm = 0; tm < 4; ++tm)
            #pragma unroll
            for (int ks = 0; ks < 2; ++ks)
                afr[tm][ks] = *(const short8*)&xs[(16 * tm + l15) * 72 + 32 * ks + quad * 8];
        #pragma unroll
        for (int i = 0; i < 3; ++i) {
            int tn = 3 * w + i;
            int n  = tn * 16 + l15;
            const __hip_bfloat16* bp = wT + n * 64 + quad * 8;
            short8 b0  = *(const short8*)bp;
            short8 b1f = *(const short8*)(bp + 32);
            #pragma unroll
            for (int tm = 0; tm < 4; ++tm) {
                f32x4 acc = {0.f, 0.f, 0.f, 0.f};
                acc = __builtin_amdgcn_mfma_f32_16x16x32_bf16(afr[tm][0], b0,  acc, 0, 0, 0);
                acc = __builtin_amdgcn_mfma_f32_16x16x32_bf16(afr[tm][1], b1f, acc, 0, 0, 0);
                int row0 = 16 * tm + 4 * quad;     // C layout: row=quad*4+r, col=l15
                if (tn < 4) {                       // Q region
                    int h = n >> 3, d = n & 7;
                    #pragma unroll
                    for (int r = 0; r < 4; ++r)
                        qh[(h * 64 + row0 + r) * 8 + d] = __float2bfloat16(acc[r]);
                } else if (tn < 8) {                // K region
                    int h = (n - 64) >> 3, d = n & 7;
                    #pragma unroll
                    for (int r = 0; r < 4; ++r)
                        kh[(h * 64 + row0 + r) * 8 + d] = __float2bfloat16(acc[r]);
                } else {                            // V region -> transposed, packed
                    int h = (n - 128) >> 3, d = n & 7;
                    union { __hip_bfloat16 h4[4]; uint2 u; } pk;
                    #pragma unroll
                    for (int r = 0; r < 4; ++r) pk.h4[r] = __float2bfloat16(acc[r]);
                    *(uint2*)&vth[(h * 8 + d) * 72 + row0] = pk.u;
                }
            }
        }
    }
    __syncthreads();   // xs dead; qh/kh/vth visible to all waves

    __hip_bfloat16* P = region0 + w * 64 * 72;     // per-wave [t][s], stride 72
    const short8 zf = {0, 0, 0, 0, 0, 0, 0, 0};

    // ---------------- phase 2: attention, head h = 2w+hh ----------------
    #pragma unroll 1
    for (int hh = 0; hh < 2; ++hh) {
        const int h = 2 * w + hh;
        // A = K (m=s, k=d<8), B = Q (n=t, k=d<8); quads 1-3 zero-padded K
        short8 kfr[4], qfr[4];
        #pragma unroll
        for (int tm = 0; tm < 4; ++tm)
            kfr[tm] = (quad == 0) ? *(const short8*)&kh[(h * 64 + 16 * tm + l15) * 8] : zf;
        #pragma unroll
        for (int tn = 0; tn < 4; ++tn)
            qfr[tn] = (quad == 0) ? *(const short8*)&qh[(h * 64 + 16 * tn + l15) * 8] : zf;

        f32x4 S[4][4];                 // S^T tiles [tm over s][tn over t], tm<=tn only
        #pragma unroll
        for (int tn = 0; tn < 4; ++tn)
            #pragma unroll
            for (int tm = 0; tm <= tn; ++tm) {
                f32x4 z = {0.f, 0.f, 0.f, 0.f};
                S[tm][tn] = __builtin_amdgcn_mfma_f32_16x16x32_bf16(kfr[tm], qfr[tn], z, 0, 0, 0);
            }

        // softmax per t-column-group tn; lane holds S^T[s=16tm+4q+r][t=16tn+l15]
        #pragma unroll
        for (int tn = 0; tn < 4; ++tn) {
            float mx = -INFINITY;
            #pragma unroll
            for (int tm = 0; tm <= tn; ++tm)
                #pragma unroll
                for (int r = 0; r < 4; ++r) {
                    float v = S[tm][tn][r] * 0.125f;            // scale C^-0.5
                    if (tm == tn && (4 * quad + r) > l15) v = -INFINITY; // causal
                    S[tm][tn][r] = v;
                    mx = fmaxf(mx, v);
                }
            mx = fmaxf(mx, __shfl_xor(mx, 16));
            mx = fmaxf(mx, __shfl_xor(mx, 32));
            float ls = 0.f;
            #pragma unroll
            for (int tm = 0; tm <= tn; ++tm)
                #pragma unroll
                for (int r = 0; r < 4; ++r) {
                    float e = __expf(S[tm][tn][r] - mx);
                    S[tm][tn][r] = e;
                    ls += e;
                }
            ls += __shfl_xor(ls, 16);
            ls += __shfl_xor(ls, 32);
            float inv = __builtin_amdgcn_rcpf(ls);
            // write normalized P[t][s], 4 bf16 packed per tile (8B)
            #pragma unroll
            for (int tm = 0; tm < 4; ++tm) {
                union { __hip_bfloat16 h4[4]; uint2 u; } pk;
                if (tm <= tn) {
                    #pragma unroll
                    for (int r = 0; r < 4; ++r)
                        pk.h4[r] = __float2bfloat16(S[tm][tn][r] * inv);
                } else {
                    pk.u.x = 0u; pk.u.y = 0u;   // fully-masked tile
                }
                *(uint2*)&P[(16 * tn + l15) * 72 + 16 * tm + 4 * quad] = pk.u;
            }
        }
        __asm__ volatile("s_waitcnt lgkmcnt(0)" ::: "memory");  // P visible to own wave

        // O = P V : A = P[t][s], B = V^T[d][s] (cols d>=8 zero)
        short8 vfr[2];
        #pragma unroll
        for (int ks = 0; ks < 2; ++ks)
            vfr[ks] = (l15 < 8) ? *(const short8*)&vth[(h * 8 + l15) * 72 + 32 * ks + 8 * quad] : zf;
        f32x4 O[4];
        #pragma unroll
        for (int tm = 0; tm < 4; ++tm) { f32x4 z = {0.f,0.f,0.f,0.f}; O[tm] = z; }
        #pragma unroll
        for (int ks = 0; ks < 2; ++ks)
            #pragma unroll
            for (int tm = 0; tm < 4; ++tm) {
                short8 a = *(const short8*)&P[(16 * tm + l15) * 72 + 32 * ks + 8 * quad];
                O[tm] = __builtin_amdgcn_mfma_f32_16x16x32_bf16(a, vfr[ks], O[tm], 0, 0, 0);
            }
        // O -> qh[h][t][d]  (att concat buffer; Q dead for this head)
        if (l15 < 8) {
            #pragma unroll
            for (int tm = 0; tm < 4; ++tm)
                #pragma unroll
                for (int r = 0; r < 4; ++r)
                    qh[(h * 64 + 16 * tm + 4 * quad + r) * 8 + l15] = __float2bfloat16(O[tm][r]);
        }
    }
    __syncthreads();   // att complete across waves

    // ---------------- phase 3: FFN ----------------
    {
        short8 afr[4][2];
        #pragma unroll
        for (int tm = 0; tm < 4; ++tm)
            #pragma unroll
            for (int ks = 0; ks < 2; ++ks)    // k=c=h*8+d, h=4ks+quad
                afr[tm][ks] = *(const short8*)&qh[((4 * ks + quad) * 64 + 16 * tm + l15) * 8];
        int j = 16 * w + l15;
        const __hip_bfloat16* bp = wT + 192 * 64 + j * 64 + quad * 8;
        short8 b0  = *(const short8*)bp;
        short8 b1f = *(const short8*)(bp + 32);
        float bias = b1v[j];
        float* yb = y + (size_t)b * 4096;
        #pragma unroll
        for (int tm = 0; tm < 4; ++tm) {
            f32x4 acc = {0.f, 0.f, 0.f, 0.f};
            acc = __builtin_amdgcn_mfma_f32_16x16x32_bf16(afr[tm][0], b0,  acc, 0, 0, 0);
            acc = __builtin_amdgcn_mfma_f32_16x16x32_bf16(afr[tm][1], b1f, acc, 0, 0, 0);
            int row0 = 16 * tm + 4 * quad;
            #pragma unroll
            for (int r = 0; r < 4; ++r)
                yb[(row0 + r) * 64 + j] = fmaxf(acc[r] + bias, 0.f);
        }
    }
}

extern "C" void kernel_launch(void* const* d_in, const int* in_sizes, int n_in,
                              void* d_out, int out_size, void* d_ws, size_t ws_size,
                              hipStream_t stream) {
    const float* x  = (const float*)d_in[0];
    const float* Wq = (const float*)d_in[1];
    const float* Wk = (const float*)d_in[2];
    const float* Wv = (const float*)d_in[3];
    const float* W1 = (const float*)d_in[4];
    const float* b1 = (const float*)d_in[5];
    float* y = (float*)d_out;
    __hip_bfloat16* ws = (__hip_bfloat16*)d_ws;

    const int B = in_sizes[0] / 4096;   // 4096
    prep_weights<<<64, 256, 0, stream>>>(Wq, Wk, Wv, W1, ws);
    mha_mfma2_kernel<<<B, 256, 0, stream>>>(x, ws, b1, y);
}

// Round 4
// 154.994 us; speedup vs baseline: 3.7232x; 1.0583x over previous
//
#include <hip/hip_runtime.h>
#include <hip/hip_bf16.h>
#include <math.h>

// B=4096, T=64, C=64, H=8, D=8. fp32 in/out.
// d_ws bf16: WqkvT[n][c] (n: q 0-63 | k 64-127 | v 128-191), then W1T[j][c].
// Main kernel: 256 thr (4 waves) per batch element.
//  phase0: x -> bf16 LDS xs[64][72]
//  phase1 (transposed GEMM): QKV^T = Wqkv^T · x^T via MFMA (A=weights, B=x).
//          C^T layout gives each thread 4 consecutive n=(h,d) -> packed uint2
//          writes to qh[h][t][d] / kh[h][s][d]; V -> vth[h][d][s] b16 (4-way).
//  phase2: per wave, heads 2w,2w+1:
//          S^T = K·Q^T (10 triangular MFMAs, k zero-padded to 32);
//          softmax per t-column: in-lane + shfl_xor(16,32);
//          P C-layout -> PV B-frag via quad-shuffle (ds_bpermute, NO LDS);
//          O^T = V^T·P (A=vth frag) -> packed uint2 into qh (att buffer).
//  phase3 (transposed): y^T tile = W1^T·att^T -> float4 stores to y.
// LDS: xs 9216 + qh 8192 + kh 8192 + vth 9216 = 34816 B -> 4 blocks/CU.

typedef __attribute__((ext_vector_type(8))) short short8;   // 8 bf16
typedef __attribute__((ext_vector_type(4))) float f32x4;

__global__ void prep_weights(const float* __restrict__ Wq,
                             const float* __restrict__ Wk,
                             const float* __restrict__ Wv,
                             const float* __restrict__ W1,
                             __hip_bfloat16* __restrict__ ws)
{
    int i = blockIdx.x * 256 + threadIdx.x;      // 16384 total
    if (i < 12288) {
        int n = i >> 6, c = i & 63;
        int sec = n >> 6;
        const float* src = (sec == 0) ? Wq : (sec == 1) ? Wk : Wv;
        int h = (n & 63) >> 3, d = n & 7;
        ws[i] = __float2bfloat16(src[h * 512 + c * 8 + d]);
    } else {
        int j = (i - 12288) >> 6, c = i & 63;
        ws[i] = __float2bfloat16(W1[c * 64 + j]);
    }
}

__device__ __forceinline__ uint32_t pk2(float a, float b) {
    union { __hip_bfloat16 h[2]; uint32_t u; } c;
    c.h[0] = __float2bfloat16(a);
    c.h[1] = __float2bfloat16(b);
    return c.u;
}

__global__ __launch_bounds__(256, 4) void mha_mfma3_kernel(
    const float* __restrict__ x,
    const __hip_bfloat16* __restrict__ wT,
    const float* __restrict__ b1v,
    float* __restrict__ y)
{
    __shared__ __align__(16) __hip_bfloat16 xs[64 * 72];
    __shared__ __align__(16) __hip_bfloat16 qh[8 * 64 * 8];   // Q[h][t][d] -> att
    __shared__ __align__(16) __hip_bfloat16 kh[8 * 64 * 8];   // K[h][s][d]
    __shared__ __align__(16) __hip_bfloat16 vth[8 * 8 * 72];  // V^T[h][d][s]

    const int b    = blockIdx.x;
    const int tid  = threadIdx.x;
    const int lane = tid & 63;
    const int w    = tid >> 6;
    const int l15  = lane & 15;
    const int quad = lane >> 4;

    // ---------------- phase 0: stage x -> bf16 ----------------
    {
        int r = tid >> 2, c0 = (tid & 3) * 16;
        const float* xp = x + (size_t)b * 4096 + r * 64 + c0;
        float4 f0 = ((const float4*)xp)[0];
        float4 f1 = ((const float4*)xp)[1];
        float4 f2 = ((const float4*)xp)[2];
        float4 f3 = ((const float4*)xp)[3];
        union { __hip_bfloat16 h[8]; float4 f; } u0, u1;
        u0.h[0] = __float2bfloat16(f0.x); u0.h[1] = __float2bfloat16(f0.y);
        u0.h[2] = __float2bfloat16(f0.z); u0.h[3] = __float2bfloat16(f0.w);
        u0.h[4] = __float2bfloat16(f1.x); u0.h[5] = __float2bfloat16(f1.y);
        u0.h[6] = __float2bfloat16(f1.z); u0.h[7] = __float2bfloat16(f1.w);
        u1.h[0] = __float2bfloat16(f2.x); u1.h[1] = __float2bfloat16(f2.y);
        u1.h[2] = __float2bfloat16(f2.z); u1.h[3] = __float2bfloat16(f2.w);
        u1.h[4] = __float2bfloat16(f3.x); u1.h[5] = __float2bfloat16(f3.y);
        u1.h[6] = __float2bfloat16(f3.z); u1.h[7] = __float2bfloat16(f3.w);
        *(float4*)&xs[r * 72 + c0]     = u0.f;
        *(float4*)&xs[r * 72 + c0 + 8] = u1.f;
    }
    __syncthreads();

    // ---------------- phase 1: QKV^T = Wqkv^T x^T ----------------
    {
        short8 xfr[4][2];   // B-frags (x), shared across this wave's m-tiles
        #pragma unroll
        for (int tt = 0; tt < 4; ++tt)
            #pragma unroll
            for (int ks = 0; ks < 2; ++ks)
                xfr[tt][ks] = *(const short8*)&xs[(16 * tt + l15) * 72 + 32 * ks + 8 * quad];
        #pragma unroll
        for (int i = 0; i < 3; ++i) {
            int mt = 3 * w + i;                       // m-tile over n=0..191
            const __hip_bfloat16* ap = wT + (16 * mt + l15) * 64 + 8 * quad;
            short8 a0 = *(const short8*)ap;
            short8 a1 = *(const short8*)(ap + 32);
            #pragma unroll
            for (int tt = 0; tt < 4; ++tt) {
                f32x4 acc = {0.f, 0.f, 0.f, 0.f};
                acc = __builtin_amdgcn_mfma_f32_16x16x32_bf16(a0, xfr[tt][0], acc, 0, 0, 0);
                acc = __builtin_amdgcn_mfma_f32_16x16x32_bf16(a1, xfr[tt][1], acc, 0, 0, 0);
                // thread holds n = 16mt+4quad+r (4 consecutive d in one h), t = 16tt+l15
                int t = 16 * tt + l15;
                union { uint32_t u2[2]; uint2 u; } pq;
                pq.u2[0] = pk2(acc[0], acc[1]);
                pq.u2[1] = pk2(acc[2], acc[3]);
                if (mt < 4) {
                    int hq = 2 * mt + (quad >> 1);
                    *(uint2*)&qh[(hq * 64 + t) * 8 + 4 * (quad & 1)] = pq.u;
                } else if (mt < 8) {
                    int hk = 2 * (mt - 4) + (quad >> 1);
                    *(uint2*)&kh[(hk * 64 + t) * 8 + 4 * (quad & 1)] = pq.u;
                } else {
                    int hv = 2 * (mt - 8) + (quad >> 1);
                    int d0 = 4 * (quad & 1);
                    #pragma unroll
                    for (int r = 0; r < 4; ++r)
                        vth[(hv * 8 + d0 + r) * 72 + t] = __float2bfloat16(acc[r]);
                }
            }
        }
    }
    __syncthreads();

    const short8 zf = {0, 0, 0, 0, 0, 0, 0, 0};
    const int sA = l15 + 32 * (quad & 1);   // shuffle srcLanes (jj>>1 == 0)
    const int sB = sA + 16;                 // (jj>>1 == 1)
    const bool lowq = (quad < 2);           // tmS = 2ks (+1 otherwise)

    // ---------------- phase 2: attention, heads h = 2w, 2w+1 ----------------
    #pragma unroll 1
    for (int hh = 0; hh < 2; ++hh) {
        const int h = 2 * w + hh;
        short8 kfr[4], qfr[4];
        #pragma unroll
        for (int tm = 0; tm < 4; ++tm)
            kfr[tm] = (quad == 0) ? *(const short8*)&kh[(h * 64 + 16 * tm + l15) * 8] : zf;
        #pragma unroll
        for (int tn = 0; tn < 4; ++tn)
            qfr[tn] = (quad == 0) ? *(const short8*)&qh[(h * 64 + 16 * tn + l15) * 8] : zf;

        f32x4 S[4][4];   // S^T tiles [tm over s][tn over t], tm<=tn only
        #pragma unroll
        for (int tn = 0; tn < 4; ++tn)
            #pragma unroll
            for (int tm = 0; tm <= tn; ++tm) {
                f32x4 z = {0.f, 0.f, 0.f, 0.f};
                S[tm][tn] = __builtin_amdgcn_mfma_f32_16x16x32_bf16(kfr[tm], qfr[tn], z, 0, 0, 0);
            }

        // softmax per t-column + pack normalized P into dword pairs
        uint32_t pkd[4][4][2];
        #pragma unroll
        for (int tn = 0; tn < 4; ++tn) {
            float mx = -INFINITY;
            #pragma unroll
            for (int tm = 0; tm <= tn; ++tm)
                #pragma unroll
                for (int r = 0; r < 4; ++r) {
                    float v = S[tm][tn][r] * 0.125f;
                    if (tm == tn && (4 * quad + r) > l15) v = -INFINITY;
                    S[tm][tn][r] = v;
                    mx = fmaxf(mx, v);
                }
            mx = fmaxf(mx, __shfl_xor(mx, 16));
            mx = fmaxf(mx, __shfl_xor(mx, 32));
            float ls = 0.f;
            #pragma unroll
            for (int tm = 0; tm <= tn; ++tm)
                #pragma unroll
                for (int r = 0; r < 4; ++r) {
                    float e = __expf(S[tm][tn][r] - mx);
                    S[tm][tn][r] = e;
                    ls += e;
                }
            ls += __shfl_xor(ls, 16);
            ls += __shfl_xor(ls, 32);
            float inv = __builtin_amdgcn_rcpf(ls);
            #pragma unroll
            for (int tm = 0; tm <= tn; ++tm) {
                pkd[tm][tn][0] = pk2(S[tm][tn][0] * inv, S[tm][tn][1] * inv);
                pkd[tm][tn][1] = pk2(S[tm][tn][2] * inv, S[tm][tn][3] * inv);
            }
        }

        // O^T = V^T · P : A = vth frag (m=d), B = P via quad-shuffle (n=t, k=s)
        short8 vfr[2];
        #pragma unroll
        for (int ks = 0; ks < 2; ++ks)
            vfr[ks] = (l15 < 8) ? *(const short8*)&vth[(h * 8 + l15) * 72 + 32 * ks + 8 * quad] : zf;

        f32x4 O[4];
        #pragma unroll
        for (int tn = 0; tn < 4; ++tn) { f32x4 z = {0.f,0.f,0.f,0.f}; O[tn] = z; }

        #pragma unroll
        for (int tn = 0; tn < 4; ++tn)
            #pragma unroll
            for (int ks = 0; ks < 2; ++ks) {
                if (2 * ks > tn) continue;              // frag entirely masked
                // dword jj holds P[t=16tn+l15][s=32ks+8quad+2jj, +1]
                uint32_t dw[4];
                #pragma unroll
                for (int jj = 0; jj < 4; ++jj) {
                    const int half = jj & 1;
                    const int sl   = (jj >> 1) ? sB : sA;
                    int vA = __shfl((int)pkd[2 * ks][tn][half], sl);
                    int vB = (2 * ks + 1 <= tn) ? __shfl((int)pkd[2 * ks + 1][tn][half], sl) : 0;
                    dw[jj] = lowq ? (uint32_t)vA : (uint32_t)vB;
                }
                union { uint32_t u[4]; short8 s; } bu;
                bu.u[0] = dw[0]; bu.u[1] = dw[1]; bu.u[2] = dw[2]; bu.u[3] = dw[3];
                O[tn] = __builtin_amdgcn_mfma_f32_16x16x32_bf16(vfr[ks], bu.s, O[tn], 0, 0, 0);
            }

        // O^T: thread (row d=4quad+r, col t=16tn+l15); rows 0-7 valid (quads 0,1)
        if (lowq) {
            #pragma unroll
            for (int tn = 0; tn < 4; ++tn) {
                union { uint32_t u2[2]; uint2 u; } po;
                po.u2[0] = pk2(O[tn][0], O[tn][1]);
                po.u2[1] = pk2(O[tn][2], O[tn][3]);
                *(uint2*)&qh[(h * 64 + 16 * tn + l15) * 8 + 4 * quad] = po.u;
            }
        }
    }
    __syncthreads();

    // ---------------- phase 3: y^T = W1^T att^T ----------------
    {
        const __hip_bfloat16* wp = wT + 12288 + (16 * w + l15) * 64 + 8 * quad;
        short8 w0 = *(const short8*)wp;
        short8 w1 = *(const short8*)(wp + 32);
        float4 bias4 = *(const float4*)&b1v[16 * w + 4 * quad];
        float* yb = y + (size_t)b * 4096;
        #pragma unroll
        for (int tt = 0; tt < 4; ++tt) {
            short8 bq0 = *(const short8*)&qh[(quad * 64 + 16 * tt + l15) * 8];       // k: h=quad
            short8 bq1 = *(const short8*)&qh[((4 + quad) * 64 + 16 * tt + l15) * 8]; // k: h=4+quad
            f32x4 acc = {0.f, 0.f, 0.f, 0.f};
            acc = __builtin_amdgcn_mfma_f32_16x16x32_bf16(w0, bq0, acc, 0, 0, 0);
            acc = __builtin_amdgcn_mfma_f32_16x16x32_bf16(w1, bq1, acc, 0, 0, 0);
            // thread: j = 16w+4quad+r (4 consecutive), t = 16tt+l15 -> float4 store
            float4 o;
            o.x = fmaxf(acc[0] + bias4.x, 0.f);
            o.y = fmaxf(acc[1] + bias4.y, 0.f);
            o.z = fmaxf(acc[2] + bias4.z, 0.f);
            o.w = fmaxf(acc[3] + bias4.w, 0.f);
            *(float4*)&yb[(16 * tt + l15) * 64 + 16 * w + 4 * quad] = o;
        }
    }
}

extern "C" void kernel_launch(void* const* d_in, const int* in_sizes, int n_in,
                              void* d_out, int out_size, void* d_ws, size_t ws_size,
                              hipStream_t stream) {
    const float* x  = (const float*)d_in[0];
    const float* Wq = (const float*)d_in[1];
    const float* Wk = (const float*)d_in[2];
    const float* Wv = (const float*)d_in[3];
    const float* W1 = (const float*)d_in[4];
    const float* b1 = (const float*)d_in[5];
    float* y = (float*)d_out;
    __hip_bfloat16* ws = (__hip_bfloat16*)d_ws;

    const int B = in_sizes[0] / 4096;   // 4096
    prep_weights<<<64, 256, 0, stream>>>(Wq, Wk, Wv, W1, ws);
    mha_mfma3_kernel<<<B, 256, 0, stream>>>(x, ws, b1, y);
}

// Round 5
// 154.846 us; speedup vs baseline: 3.7268x; 1.0010x over previous
//
#include <hip/hip_runtime.h>
#include <hip/hip_bf16.h>
#include <math.h>

// B=4096, T=64, C=64, H=8, D=8. fp32 in/out.
// d_ws bf16: WqkvT[n][c] (n: q 0-63 | k 64-127 | v 128-191), then W1T[j][c].
// Main kernel: 256 thr (4 waves) per batch element.
//  phase0: x -> bf16 LDS xs[64][72]       (region0)
//  phase1: QKV^T = Wqkv^T x^T via MFMA (A=weights, B=x). All waves load x
//          frags to regs, BARRIER, then vth overlays xs (region0 reuse).
//          C^T gives 4 consecutive n per thread -> packed uint2 to qh/kh,
//          scalar b16 to vth[h][d][s].
//  phase2: per wave, heads 2w,2w+1: S^T = K Q^T (10 triangular MFMAs,
//          k zero-padded); max-free softmax: e = exp2(s * 0.125*log2e)
//          (scores bounded => no overflow), row-sum in-lane + shfl_xor(16,32);
//          unnormalized P -> quad-shuffle -> B-frags; O^T = V^T P;
//          normalize O by per-column inv (each lane owns its column's sum);
//          packed uint2 into qh (att buffer).
//  phase3: y^T = W1^T att^T -> float4 stores.
// LDS: region0 9216 (xs|vth) + qh 8192 + kh 8192 = 25600 B -> 6 blocks/CU.

typedef __attribute__((ext_vector_type(8))) short short8;   // 8 bf16
typedef __attribute__((ext_vector_type(4))) float f32x4;

__global__ void prep_weights(const float* __restrict__ Wq,
                             const float* __restrict__ Wk,
                             const float* __restrict__ Wv,
                             const float* __restrict__ W1,
                             __hip_bfloat16* __restrict__ ws)
{
    int i = blockIdx.x * 256 + threadIdx.x;      // 16384 total
    if (i < 12288) {
        int n = i >> 6, c = i & 63;
        int sec = n >> 6;
        const float* src = (sec == 0) ? Wq : (sec == 1) ? Wk : Wv;
        int h = (n & 63) >> 3, d = n & 7;
        ws[i] = __float2bfloat16(src[h * 512 + c * 8 + d]);
    } else {
        int j = (i - 12288) >> 6, c = i & 63;
        ws[i] = __float2bfloat16(W1[c * 64 + j]);
    }
}

__device__ __forceinline__ uint32_t pk2(float a, float b) {
    __hip_bfloat162 h2 = __float22bfloat162_rn(make_float2(a, b));
    union { __hip_bfloat162 h; uint32_t u; } c;
    c.h = h2;
    return c.u;
}

__global__ __launch_bounds__(256, 6) void mha_mfma4_kernel(
    const float* __restrict__ x,
    const __hip_bfloat16* __restrict__ wT,
    const float* __restrict__ b1v,
    float* __restrict__ y)
{
    __shared__ __align__(16) __hip_bfloat16 region0[64 * 72]; // xs, later vth
    __shared__ __align__(16) __hip_bfloat16 qh[8 * 64 * 8];   // Q[h][t][d] -> att
    __shared__ __align__(16) __hip_bfloat16 kh[8 * 64 * 8];   // K[h][s][d]

    __hip_bfloat16* xs  = region0;            // [64][72]
    __hip_bfloat16* vth = region0;            // V^T[h][d][s], [64][72] overlay

    const int b    = blockIdx.x;
    const int tid  = threadIdx.x;
    const int lane = tid & 63;
    const int w    = tid >> 6;
    const int l15  = lane & 15;
    const int quad = lane >> 4;

    // ---------------- phase 0: stage x -> bf16 ----------------
    {
        int r = tid >> 2, c0 = (tid & 3) * 16;
        const float* xp = x + (size_t)b * 4096 + r * 64 + c0;
        float4 f0 = ((const float4*)xp)[0];
        float4 f1 = ((const float4*)xp)[1];
        float4 f2 = ((const float4*)xp)[2];
        float4 f3 = ((const float4*)xp)[3];
        union { __hip_bfloat16 h[8]; float4 f; } u0, u1;
        u0.h[0] = __float2bfloat16(f0.x); u0.h[1] = __float2bfloat16(f0.y);
        u0.h[2] = __float2bfloat16(f0.z); u0.h[3] = __float2bfloat16(f0.w);
        u0.h[4] = __float2bfloat16(f1.x); u0.h[5] = __float2bfloat16(f1.y);
        u0.h[6] = __float2bfloat16(f1.z); u0.h[7] = __float2bfloat16(f1.w);
        u1.h[0] = __float2bfloat16(f2.x); u1.h[1] = __float2bfloat16(f2.y);
        u1.h[2] = __float2bfloat16(f2.z); u1.h[3] = __float2bfloat16(f2.w);
        u1.h[4] = __float2bfloat16(f3.x); u1.h[5] = __float2bfloat16(f3.y);
        u1.h[6] = __float2bfloat16(f3.z); u1.h[7] = __float2bfloat16(f3.w);
        *(float4*)&xs[r * 72 + c0]     = u0.f;
        *(float4*)&xs[r * 72 + c0 + 8] = u1.f;
    }
    __syncthreads();

    // ---------------- phase 1: QKV^T = Wqkv^T x^T ----------------
    {
        short8 xfr[4][2];   // B-frags (x)
        #pragma unroll
        for (int tt = 0; tt < 4; ++tt)
            #pragma unroll
            for (int ks = 0; ks < 2; ++ks)
                xfr[tt][ks] = *(const short8*)&xs[(16 * tt + l15) * 72 + 32 * ks + 8 * quad];
        __syncthreads();    // xs fully consumed; region0 now writable as vth

        #pragma unroll
        for (int i = 0; i < 3; ++i) {
            int mt = 3 * w + i;                       // m-tile over n=0..191
            const __hip_bfloat16* ap = wT + (16 * mt + l15) * 64 + 8 * quad;
            short8 a0 = *(const short8*)ap;
            short8 a1 = *(const short8*)(ap + 32);
            #pragma unroll
            for (int tt = 0; tt < 4; ++tt) {
                f32x4 acc = {0.f, 0.f, 0.f, 0.f};
                acc = __builtin_amdgcn_mfma_f32_16x16x32_bf16(a0, xfr[tt][0], acc, 0, 0, 0);
                acc = __builtin_amdgcn_mfma_f32_16x16x32_bf16(a1, xfr[tt][1], acc, 0, 0, 0);
                // thread holds n = 16mt+4quad+r, t = 16tt+l15
                int t = 16 * tt + l15;
                union { uint32_t u2[2]; uint2 u; } pq;
                pq.u2[0] = pk2(acc[0], acc[1]);
                pq.u2[1] = pk2(acc[2], acc[3]);
                if (mt < 4) {
                    int hq = 2 * mt + (quad >> 1);
                    *(uint2*)&qh[(hq * 64 + t) * 8 + 4 * (quad & 1)] = pq.u;
                } else if (mt < 8) {
                    int hk = 2 * (mt - 4) + (quad >> 1);
                    *(uint2*)&kh[(hk * 64 + t) * 8 + 4 * (quad & 1)] = pq.u;
                } else {
                    int hv = 2 * (mt - 8) + (quad >> 1);
                    int d0 = 4 * (quad & 1);
                    #pragma unroll
                    for (int r = 0; r < 4; ++r)
                        vth[(hv * 8 + d0 + r) * 72 + t] = __float2bfloat16(acc[r]);
                }
            }
        }
    }
    __syncthreads();

    const short8 zf = {0, 0, 0, 0, 0, 0, 0, 0};
    const int sA = l15 + 32 * (quad & 1);   // shuffle srcLanes
    const int sB = sA + 16;
    const bool lowq = (quad < 2);
    const float SC = 0.125f * 1.4426950408889634f;   // C^-0.5 * log2(e)

    // ---------------- phase 2: attention, heads h = 2w, 2w+1 ----------------
    #pragma unroll 1
    for (int hh = 0; hh < 2; ++hh) {
        const int h = 2 * w + hh;
        short8 kfr[4], qfr[4];
        #pragma unroll
        for (int tm = 0; tm < 4; ++tm)
            kfr[tm] = (quad == 0) ? *(const short8*)&kh[(h * 64 + 16 * tm + l15) * 8] : zf;
        #pragma unroll
        for (int tn = 0; tn < 4; ++tn)
            qfr[tn] = (quad == 0) ? *(const short8*)&qh[(h * 64 + 16 * tn + l15) * 8] : zf;

        f32x4 S[4][4];   // S^T tiles [tm over s][tn over t], tm<=tn only
        #pragma unroll
        for (int tn = 0; tn < 4; ++tn)
            #pragma unroll
            for (int tm = 0; tm <= tn; ++tm) {
                f32x4 z = {0.f, 0.f, 0.f, 0.f};
                S[tm][tn] = __builtin_amdgcn_mfma_f32_16x16x32_bf16(kfr[tm], qfr[tn], z, 0, 0, 0);
            }

        // max-free softmax (scores bounded) + pack unnormalized P
        uint32_t pkd[4][4][2];
        float inv4[4];
        #pragma unroll
        for (int tn = 0; tn < 4; ++tn) {
            float ls = 0.f;
            #pragma unroll
            for (int tm = 0; tm <= tn; ++tm)
                #pragma unroll
                for (int r = 0; r < 4; ++r) {
                    float e = __builtin_exp2f(S[tm][tn][r] * SC);
                    if (tm == tn && (4 * quad + r) > l15) e = 0.f;   // causal
                    S[tm][tn][r] = e;
                    ls += e;
                }
            ls += __shfl_xor(ls, 16);
            ls += __shfl_xor(ls, 32);
            inv4[tn] = __builtin_amdgcn_rcpf(ls);
            #pragma unroll
            for (int tm = 0; tm <= tn; ++tm) {
                pkd[tm][tn][0] = pk2(S[tm][tn][0], S[tm][tn][1]);
                pkd[tm][tn][1] = pk2(S[tm][tn][2], S[tm][tn][3]);
            }
        }

        // O^T = V^T · P : A = vth frag (m=d), B = P via quad-shuffle (n=t, k=s)
        short8 vfr[2];
        #pragma unroll
        for (int ks = 0; ks < 2; ++ks)
            vfr[ks] = (l15 < 8) ? *(const short8*)&vth[(h * 8 + l15) * 72 + 32 * ks + 8 * quad] : zf;

        f32x4 O[4];
        #pragma unroll
        for (int tn = 0; tn < 4; ++tn) { f32x4 z = {0.f,0.f,0.f,0.f}; O[tn] = z; }

        #pragma unroll
        for (int tn = 0; tn < 4; ++tn)
            #pragma unroll
            for (int ks = 0; ks < 2; ++ks) {
                if (2 * ks > tn) continue;              // frag entirely masked
                // dword jj holds P[t=16tn+l15][s=32ks+8quad+2jj, +1]
                uint32_t dw[4];
                #pragma unroll
                for (int jj = 0; jj < 4; ++jj) {
                    const int half = jj & 1;
                    const int sl   = (jj >> 1) ? sB : sA;
                    int vA = __shfl((int)pkd[2 * ks][tn][half], sl);
                    int vB = (2 * ks + 1 <= tn) ? __shfl((int)pkd[2 * ks + 1][tn][half], sl) : 0;
                    dw[jj] = lowq ? (uint32_t)vA : (uint32_t)vB;
                }
                union { uint32_t u[4]; short8 s; } bu;
                bu.u[0] = dw[0]; bu.u[1] = dw[1]; bu.u[2] = dw[2]; bu.u[3] = dw[3];
                O[tn] = __builtin_amdgcn_mfma_f32_16x16x32_bf16(vfr[ks], bu.s, O[tn], 0, 0, 0);
            }

        // O^T: thread (row d=4quad+r, col t=16tn+l15); rows 0-7 valid (quads 0,1)
        // normalize here: every lane holds inv for its own t column.
        if (lowq) {
            #pragma unroll
            for (int tn = 0; tn < 4; ++tn) {
                float iv = inv4[tn];
                union { uint32_t u2[2]; uint2 u; } po;
                po.u2[0] = pk2(O[tn][0] * iv, O[tn][1] * iv);
                po.u2[1] = pk2(O[tn][2] * iv, O[tn][3] * iv);
                *(uint2*)&qh[(h * 64 + 16 * tn + l15) * 8 + 4 * quad] = po.u;
            }
        }
    }
    __syncthreads();

    // ---------------- phase 3: y^T = W1^T att^T ----------------
    {
        const __hip_bfloat16* wp = wT + 12288 + (16 * w + l15) * 64 + 8 * quad;
        short8 w0 = *(const short8*)wp;
        short8 w1 = *(const short8*)(wp + 32);
        float4 bias4 = *(const float4*)&b1v[16 * w + 4 * quad];
        float* yb = y + (size_t)b * 4096;
        #pragma unroll
        for (int tt = 0; tt < 4; ++tt) {
            short8 bq0 = *(const short8*)&qh[(quad * 64 + 16 * tt + l15) * 8];       // k: h=quad
            short8 bq1 = *(const short8*)&qh[((4 + quad) * 64 + 16 * tt + l15) * 8]; // k: h=4+quad
            f32x4 acc = {0.f, 0.f, 0.f, 0.f};
            acc = __builtin_amdgcn_mfma_f32_16x16x32_bf16(w0, bq0, acc, 0, 0, 0);
            acc = __builtin_amdgcn_mfma_f32_16x16x32_bf16(w1, bq1, acc, 0, 0, 0);
            float4 o;
            o.x = fmaxf(acc[0] + bias4.x, 0.f);
            o.y = fmaxf(acc[1] + bias4.y, 0.f);
            o.z = fmaxf(acc[2] + bias4.z, 0.f);
            o.w = fmaxf(acc[3] + bias4.w, 0.f);
            *(float4*)&yb[(16 * tt + l15) * 64 + 16 * w + 4 * quad] = o;
        }
    }
}

extern "C" void kernel_launch(void* const* d_in, const int* in_sizes, int n_in,
                              void* d_out, int out_size, void* d_ws, size_t ws_size,
                              hipStream_t stream) {
    const float* x  = (const float*)d_in[0];
    const float* Wq = (const float*)d_in[1];
    const float* Wk = (const float*)d_in[2];
    const float* Wv = (const float*)d_in[3];
    const float* W1 = (const float*)d_in[4];
    const float* b1 = (const float*)d_in[5];
    float* y = (float*)d_out;
    __hip_bfloat16* ws = (__hip_bfloat16*)d_ws;

    const int B = in_sizes[0] / 4096;   // 4096
    prep_weights<<<64, 256, 0, stream>>>(Wq, Wk, Wv, W1, ws);
    mha_mfma4_kernel<<<B, 256, 0, stream>>>(x, ws, b1, y);
}